// Round 1
// baseline (422.621 us; speedup 1.0000x reference)
//
#include <hip/hip_runtime.h>

// Shift: out[b,c,h,w] = x[b,c, clamp(h + trunc(ypos[h]*stride), 0, H-1),
//                              clamp(w + trunc(xpos[w]*stride), 0, W-1)]
// B=16, C=64, H=256, W=256, fp32.
//
// sh is row-uniform -> stage source rows into LDS with fully-coalesced float4
// reads. This version also makes the STORE side float4: each thread owns 4
// consecutive output columns, gathers them from LDS, and writes one
// global_store_dwordx4 (4x fewer store instrs + addr VALU than dword stores).
// The gather is ~8-way LDS bank-conflicted (stride-4 element groups), but at
// ~1100 cyc/block vs ~3200 cyc/block of HBM share it stays hidden.

constexpr int Bc = 16;
constexpr int Cc = 64;
constexpr int Hc = 256;
constexpr int Wc = 256;
constexpr int ROWS = 16;   // output rows per block; LDS = 16*256*4 = 16 KiB

__global__ __launch_bounds__(256) void shift_kernel(
    const float* __restrict__ x,
    const float* __restrict__ xpos,
    const float* __restrict__ ypos,
    const int* __restrict__ stride_p,
    float* __restrict__ out)
{
    __shared__ float lds[ROWS][Wc];

    const int stride = *stride_p;
    const int t  = threadIdx.x;
    const int wv = t >> 6;                 // wave id 0..3
    const int ln = t & 63;                 // lane 0..63

    const int plane = blockIdx.x >> 4;             // (b*C + c), 16 blocks per plane
    const int h0    = (blockIdx.x & 15) * ROWS;

    const float* __restrict__ src_plane = x + (long long)plane * Hc * Wc;

    // ---- Phase 1: stage 16 source rows, coalesced float4 (1 KiB/row/wave) ----
    // iter k, wave wv handles LDS row r = wv + 4k; lane ln loads cols 4ln..4ln+3.
#pragma unroll
    for (int k = 0; k < 4; ++k) {
        const int r = wv + 4 * k;
        const int h = h0 + r;
        int sh = h + (int)(ypos[h] * (float)stride);   // row-uniform
        sh = min(max(sh, 0), Hc - 1);
        const float4 v = *reinterpret_cast<const float4*>(src_plane + sh * Wc + ln * 4);
        *reinterpret_cast<float4*>(&lds[r][ln * 4]) = v;
    }

    // ---- Phase 2 prep (overlaps staging latency): this thread's 4 columns ----
    const int c0 = ln * 4;
    const float4 xp = *reinterpret_cast<const float4*>(xpos + c0);
    int sw0 = c0 + 0 + (int)(xp.x * (float)stride);
    int sw1 = c0 + 1 + (int)(xp.y * (float)stride);
    int sw2 = c0 + 2 + (int)(xp.z * (float)stride);
    int sw3 = c0 + 3 + (int)(xp.w * (float)stride);
    sw0 = min(max(sw0, 0), Wc - 1);
    sw1 = min(max(sw1, 0), Wc - 1);
    sw2 = min(max(sw2, 0), Wc - 1);
    sw3 = min(max(sw3, 0), Wc - 1);

    __syncthreads();

    // ---- Phase 2: gather 4 consecutive columns from LDS, float4 stores ----
    // iter k, wave wv stores output row r = wv + 4k as one contiguous 1 KiB
    // wave-level dwordx4 store.
    float* __restrict__ dst = out + ((long long)plane * Hc + h0) * Wc + c0;
#pragma unroll
    for (int k = 0; k < 4; ++k) {
        const int r = wv + 4 * k;
        float4 v;
        v.x = lds[r][sw0];
        v.y = lds[r][sw1];
        v.z = lds[r][sw2];
        v.w = lds[r][sw3];
        *reinterpret_cast<float4*>(dst + r * Wc) = v;
    }
}

extern "C" void kernel_launch(void* const* d_in, const int* in_sizes, int n_in,
                              void* d_out, int out_size, void* d_ws, size_t ws_size,
                              hipStream_t stream)
{
    const float* x    = (const float*)d_in[0];
    const float* xpos = (const float*)d_in[1];
    const float* ypos = (const float*)d_in[2];
    const int* stride = (const int*)d_in[3];
    float* out        = (float*)d_out;

    const int blocks = Bc * Cc * (Hc / ROWS);   // 16*64*16 = 16384
    shift_kernel<<<blocks, 256, 0, stream>>>(x, xpos, ypos, stride, out);
}